// Round 22
// baseline (130.244 us; speedup 1.0000x reference)
//
#include <hip/hip_runtime.h>
#include <hip/hip_bf16.h>
#include <stdint.h>

typedef __bf16 bf16;
typedef __bf16 bf16x8 __attribute__((ext_vector_type(8)));
typedef __bf16 bf16x4 __attribute__((ext_vector_type(4)));
typedef float f32x4 __attribute__((ext_vector_type(4)));

#define T_SEQ 2048
#define DIM_ 512
#define NH_ 8
#define NKV_ 4
#define HD_ 64
#define BT_ (8 * T_SEQ) /* 16384 token rows */
#define NEG_INF (-1e30f)
#define EPS_ 1.1920928955078125e-07f
#define QSCALE 0.18033688011112042f /* 0.125 * log2(e): attn uses exp2 */
#define SMAX 12.0f /* fixed softmax max: |score| <= 64*0.125*log2e = 11.54 < 12 */

// workspace layout (bytes)
#define OFF_XB   (size_t)(0)
#define OFF_WQKV (size_t)(16777216)
#define OFF_WP   (size_t)(17825792)
#define OFF_COS  (size_t)(18350080)
#define OFF_SIN  (size_t)(18612224)
#define OFF_QT   (size_t)(18874368)
#define OFF_KT   (size_t)(35651584)
#define OFF_VT   (size_t)(44040192)
#define OFF_Y    (size_t)(52428800)
#define WS_NEEDED (size_t)(69206016)

__device__ inline void mfma16(f32x4& acc, bf16x8 a, bf16x8 b) {
    acc = __builtin_amdgcn_mfma_f32_16x16x32_bf16(a, b, acc, 0, 0, 0);
}

// async global->LDS, 16B per lane. LDS dest is wave-uniform base + lane*16;
// the per-lane GLOBAL address carries the permutation (m173 pattern).
typedef const __attribute__((address_space(1))) uint8_t* gas_ptr;
typedef __attribute__((address_space(3))) uint8_t* las_ptr;
__device__ inline void gload16(const bf16* g, bf16* l) {
    __builtin_amdgcn_global_load_lds((gas_ptr)(const void*)g, (las_ptr)(void*)l, 16, 0, 0);
}

__device__ inline bf16x4 cvt4(const float4& a) {
    bf16x4 v;
    v[0] = (bf16)a.x; v[1] = (bf16)a.y; v[2] = (bf16)a.z; v[3] = (bf16)a.w;
    return v;
}

// ---------------- prep: VECTORIZED fp32 -> bf16 casts + stacked W + rope tables ----------------
__global__ void prep_kernel(const float* __restrict__ x, const float* __restrict__ wq,
                            const float* __restrict__ wk, const float* __restrict__ wv,
                            const float* __restrict__ wp,
                            bf16* __restrict__ xb, bf16* __restrict__ wqkv,
                            bf16* __restrict__ wpb, float* __restrict__ cosT,
                            float* __restrict__ sinT) {
    int tid = blockIdx.x * blockDim.x + threadIdx.x;
    int stride = gridDim.x * blockDim.x;
    for (int i = tid; i < BT_ * DIM_ / 4; i += stride)
        *(bf16x4*)(xb + (size_t)i * 4) = cvt4(((const float4*)x)[i]);
    for (int i = tid; i < 1024 * 512 / 4; i += stride) {
        int e = i * 4;
        int j = e >> 9, k = e & 511;
        const float* src;
        if (j < 512) src = wq + (size_t)j * 512 + k;
        else if (j < 768) src = wk + (size_t)(j - 512) * 512 + k;
        else src = wv + (size_t)(j - 768) * 512 + k;
        *(bf16x4*)(wqkv + (size_t)e) = cvt4(*(const float4*)src);
    }
    for (int i = tid; i < 512 * 512 / 4; i += stride)
        *(bf16x4*)(wpb + (size_t)i * 4) = cvt4(((const float4*)wp)[i]);
    for (int i = tid; i < T_SEQ * 32; i += stride) {
        int t = i >> 5, d = i & 31;
        float inv = powf(10000.0f, -(float)d * (1.0f / 32.0f));
        float f = (float)t * inv;
        cosT[i] = cosf(f);
        sinT[i] = sinf(f);
    }
}

// ---------------- QKV GEMM: 256x128 tile, 8 waves + fused RMSNorm + RoPE epilogue (R21) ----------------
__global__ __launch_bounds__(512, 4) void qkv_gemm(const bf16* __restrict__ A,
                                                   const bf16* __restrict__ B,
                                                   bf16* __restrict__ qt,
                                                   bf16* __restrict__ kt,
                                                   bf16* __restrict__ vt,
                                                   const float* __restrict__ cosT,
                                                   const float* __restrict__ sinT) {
    __shared__ __align__(16) char smem[49152]; // loop: A(32K)+B(16K); epilogue: 8x 32x66 bf16 (33.8K)
    bf16* As = (bf16*)smem;
    bf16* Bs = (bf16*)(smem + 32768);
    const int tid = threadIdx.x, lane = tid & 63, wid = tid >> 6;
    const int wr = wid >> 1, wc = wid & 1;   // 4x2 wave grid over 256x128
    const int lm = lane & 15, hi = lane >> 4;
    const int bid = blockIdx.x;               // 512 blocks: 64 row-panels x 8 col-panels
    const int swz = (bid & 7) * 64 + (bid >> 3); // XCD owns one col panel
    const int brow = (swz & 63) * 256;
    const int bcol = (swz >> 6) * 128;

    f32x4 acc[4][4] = {};
    for (int k0 = 0; k0 < 512; k0 += 64) {
        __syncthreads();
#pragma unroll
        for (int i = 0; i < 4; ++i) {         // A: 2048 chunks (256x64 bf16)
            int c = i * 512 + tid;
            int f = c >> 6, l = c & 63;
            int row = (f >> 1) * 16 + (l & 15);
            int kc = (f & 1) * 32 + (l >> 4) * 8;
            gload16(A + (size_t)(brow + row) * 512 + k0 + kc, As + c * 8);
        }
#pragma unroll
        for (int i = 0; i < 2; ++i) {         // B: 1024 chunks (128x64 bf16)
            int c = i * 512 + tid;
            int f = c >> 6, l = c & 63;
            int row = (f >> 1) * 16 + (l & 15);
            int kc = (f & 1) * 32 + (l >> 4) * 8;
            gload16(B + (size_t)(bcol + row) * 512 + k0 + kc, Bs + c * 8);
        }
        asm volatile("s_waitcnt vmcnt(0)" ::: "memory");
        __syncthreads();
#pragma unroll
        for (int kk = 0; kk < 2; ++kk) {
            bf16x8 af[4], bfr[4];
#pragma unroll
            for (int m = 0; m < 4; ++m)
                af[m] = *(const bf16x8*)(As + (((wr * 4 + m) * 2 + kk) * 64 + lane) * 8);
#pragma unroll
            for (int n = 0; n < 4; ++n)
                bfr[n] = *(const bf16x8*)(Bs + (((wc * 4 + n) * 2 + kk) * 64 + lane) * 8);
            __builtin_amdgcn_s_setprio(1);
#pragma unroll
            for (int m = 0; m < 4; ++m)
#pragma unroll
                for (int n = 0; n < 4; ++n) mfma16(acc[m][n], af[m], bfr[n]);
            __builtin_amdgcn_s_setprio(0);
        }
    }
    __syncthreads(); // staging reads complete; smem now the per-wave transpose buffers

    bf16* Tb = (bf16*)smem + wid * 2112; // 32 x 66 per wave (wave-private)
    const int wcol = bcol + wc * 64;     // 64-aligned -> whole wave is one head type
    const int ctype = (wcol < 512) ? 0 : (wcol < 768 ? 1 : 2);
    const int i0 = brow + wr * 64;
    const int b = i0 >> 11, tt = i0 & (T_SEQ - 1);

#pragma unroll
    for (int h2 = 0; h2 < 2; ++h2) {
        if (ctype < 2) {
#pragma unroll
            for (int mm = 0; mm < 2; ++mm) {
                const int m = h2 * 2 + mm;
#pragma unroll
                for (int r = 0; r < 4; ++r) {
                    float v0 = acc[m][0][r], v1 = acc[m][1][r];
                    float v2 = acc[m][2][r], v3 = acc[m][3][r];
                    float ss = v0 * v0 + v1 * v1 + v2 * v2 + v3 * v3;
                    ss += __shfl_xor(ss, 1);
                    ss += __shfl_xor(ss, 2);
                    ss += __shfl_xor(ss, 4);
                    ss += __shfl_xor(ss, 8);
                    float rinv = rsqrtf(ss * (1.0f / 64.0f) + EPS_);
                    v0 *= rinv; v1 *= rinv; v2 *= rinv; v3 *= rinv;
                    int rl = m * 16 + hi * 4 + r;
                    int t = (i0 + rl) & (T_SEQ - 1);
                    float c0 = cosT[t * 32 + lm], s0 = sinT[t * 32 + lm];
                    float c1 = cosT[t * 32 + 16 + lm], s1 = sinT[t * 32 + 16 + lm];
                    float o0 = v0 * c0 + v2 * s0;
                    float o2 = v2 * c0 - v0 * s0;
                    float o1 = v1 * c1 + v3 * s1;
                    float o3 = v3 * c1 - v1 * s1;
                    if (ctype == 0) { o0 *= QSCALE; o1 *= QSCALE; o2 *= QSCALE; o3 *= QSCALE; }
                    int rloc = mm * 16 + hi * 4 + r;
                    Tb[rloc * 66 + lm]      = (bf16)o0;
                    Tb[rloc * 66 + 16 + lm] = (bf16)o1;
                    Tb[rloc * 66 + 32 + lm] = (bf16)o2;
                    Tb[rloc * 66 + 48 + lm] = (bf16)o3;
                }
            }
        } else {
#pragma unroll
            for (int m = 0; m < 4; ++m)
#pragma unroll
                for (int nn = 0; nn < 2; ++nn) {
                    const int n = h2 * 2 + nn;
#pragma unroll
                    for (int r = 0; r < 4; ++r)
                        Tb[(nn * 16 + lm) * 66 + m * 16 + hi * 4 + r] = (bf16)acc[m][n][r];
                }
        }
        // wave-private buffer: in-wave lgkmcnt ordering suffices (same pattern as attn epilogue)
#pragma unroll
        for (int pp = 0; pp < 4; ++pp) {
            int row = pp * 8 + (lane >> 3); // 0..31
            int ch = lane & 7;
            bf16x8 val = *(const bf16x8*)(Tb + row * 66 + ch * 8);
            if (ctype == 0) {
                int head = wcol >> 6;
                *(bf16x8*)(qt + ((size_t)((b << 3) + head) * T_SEQ + tt + h2 * 32 + row) * 64 + ch * 8) = val;
            } else if (ctype == 1) {
                int head = (wcol - 512) >> 6;
                *(bf16x8*)(kt + ((size_t)((b << 2) + head) * T_SEQ + tt + h2 * 32 + row) * 64 + ch * 8) = val;
            } else {
                int head = (wcol - 768) >> 6;
                *(bf16x8*)(vt + ((size_t)((b << 2) + head) * 64 + h2 * 32 + row) * T_SEQ + tt + ch * 8) = val;
            }
        }
    }
}

// ---------------- causal GQA flash attention: 8-wave blocks, 128-row panels (R17/R20) ----------------
__global__ __launch_bounds__(512, 4) void attn_kernel(const bf16* __restrict__ qt,
                                                      const bf16* __restrict__ kt,
                                                      const bf16* __restrict__ vt,
                                                      bf16* __restrict__ y) {
    __shared__ bf16 Klds[4096];       // 8 frag-slots x 64 lanes x 8 elem
    __shared__ bf16 Vlds[4096];
    __shared__ bf16 Plds[8][1152];    // per-wave P (stride 40) / epilogue transpose (stride 72)
    const int tid = threadIdx.x;
    const int lane = tid & 63, wid = tid >> 6;
    const int lm = lane & 15, hi = lane >> 4;
    const int bid = blockIdx.x;
    const int s4 = bid >> 8;               // 0..3 (dispatch round; 0 = heaviest)
    const int g4 = (bid >> 6) & 3;         // 0..3 (CU slot)
    const int bh = bid & 63;
    const int p = 4 * (3 - s4) + ((g4 + s4) & 3); // Latin square over 16 panels
    const int b = bh >> 3, h = bh & 7, hv = h >> 1;
    const bf16* Q = qt + (size_t)bh * T_SEQ * HD_;
    const bf16* K = kt + (size_t)(b * NKV_ + hv) * T_SEQ * HD_;
    const bf16* V = vt + (size_t)(b * NKV_ + hv) * HD_ * T_SEQ;
    const int qB = p * 128;
    const int qw = qB + wid * 16;
    bf16* Pl = &Plds[wid][0];

    // staging geometry: 512 threads x 1 chunk = full 64x64 K tile (and V tile)
    const int sl0 = tid >> 6, l0 = tid & 63;
    const int gr0 = (sl0 >> 1) * 16 + (l0 & 15);
    const int gc0 = (sl0 & 1) * 32 + (l0 >> 4) * 8;
    const bf16* kg0 = K + (size_t)gr0 * HD_ + gc0;
    const bf16* vg0 = V + (size_t)gr0 * T_SEQ + gc0;
    bf16* kd0 = Klds + (size_t)tid * 8;
    bf16* vd0 = Vlds + (size_t)tid * 8;

    // Q fragments (B-side): lane holds Q[q=qw+lm][d = 32*kk + 8*hi + j]
    bf16x8 qf[2];
#pragma unroll
    for (int kk = 0; kk < 2; ++kk)
        qf[kk] = *(const bf16x8*)(Q + (size_t)(qw + lm) * HD_ + 32 * kk + 8 * hi);

    bf16x8 vones;
#pragma unroll
    for (int j = 0; j < 8; ++j) vones[j] = (bf16)1.0f;

    f32x4 o[4] = {};
    f32x4 lacc = {};

    const int nt = (qB >> 6) + 2;
    for (int t = 0; t < nt; ++t) {
        const int kv0 = t << 6;
        __syncthreads(); // previous tile's compute done before overwrite
        {
            size_t ko = (size_t)kv0 * HD_, vo = (size_t)kv0;
            gload16(kg0 + ko, kd0);
            gload16(vg0 + vo, vd0);
        }
        asm volatile("s_waitcnt vmcnt(0)" ::: "memory");
        __syncthreads();

        if (kv0 <= qw + 15) { // wave-uniform: skip fully-masked tiles
            // ---- QK^T (swapped): s[n] rows = kv (16n+4hi+r), col = q (lm)
            f32x4 s[4] = {};
#pragma unroll
            for (int kk = 0; kk < 2; ++kk) {
                bf16x8 kf[4];
#pragma unroll
                for (int n = 0; n < 4; ++n)
                    kf[n] = *(const bf16x8*)(Klds + ((n * 2 + kk) * 64 + lane) * 8);
                __builtin_amdgcn_s_setprio(1);
#pragma unroll
                for (int n = 0; n < 4; ++n) mfma16(s[n], kf[n], qf[kk]);
                __builtin_amdgcn_s_setprio(0);
            }
            const bool partial = (kv0 + 63 > qw);
            const int qg = qw + lm;
            bf16x4 pw[4];
#pragma unroll
            for (int n = 0; n < 4; ++n)
#pragma unroll
                for (int r = 0; r < 4; ++r) {
                    float xv = s[n][r];
                    if (partial)
                        xv = ((kv0 + 16 * n + 4 * hi + r) <= qg) ? xv : NEG_INF;
                    pw[n][r] = (bf16)__builtin_amdgcn_exp2f(xv - SMAX); // fixed max
                }
            // ---- PV (swapped) in 2 kk-phases; denominator via ones-row MFMA
#pragma unroll
            for (int kk = 0; kk < 2; ++kk) {
                *(bf16x4*)(Pl + lm * 40 + 4 * hi)      = pw[2 * kk];
                *(bf16x4*)(Pl + lm * 40 + 16 + 4 * hi) = pw[2 * kk + 1];
                bf16x8 vf[4], pf;
                pf = *(const bf16x8*)(Pl + lm * 40 + 8 * hi);
#pragma unroll
                for (int nd = 0; nd < 4; ++nd)
                    vf[nd] = *(const bf16x8*)(Vlds + ((nd * 2 + kk) * 64 + lane) * 8);
                __builtin_amdgcn_s_setprio(1);
#pragma unroll
                for (int nd = 0; nd < 4; ++nd) mfma16(o[nd], vf[nd], pf);
                mfma16(lacc, vones, pf); // row of ones: lacc[*] = sum_k P[k][q=lm]
                __builtin_amdgcn_s_setprio(0);
            }
        }
    }

    // epilogue: normalize by lacc[0] (every lane holds its q-column's sum), transpose via LDS
    float rcl = 1.0f / lacc[0];
#pragma unroll
    for (int nd = 0; nd < 4; ++nd) {
        bf16x4 ov;
#pragma unroll
        for (int r = 0; r < 4; ++r) ov[r] = (bf16)(o[nd][r] * rcl);
        *(bf16x4*)(Pl + lm * 72 + nd * 16 + 4 * hi) = ov;
    }
#pragma unroll
    for (int it = 0; it < 2; ++it) {
        int chunk = it * 64 + lane;
        int row = chunk >> 3, dc = (chunk & 7) * 8;
        bf16x8 val = *(const bf16x8*)(Pl + row * 72 + dc);
        *(bf16x8*)(y + (size_t)(b * T_SEQ + qw + row) * DIM_ + h * HD_ + dc) = val;
    }
}

// ---------------- output projection: 256x128 tile, 8 waves (mirror of R21 qkv re-tile) ----------------
__global__ __launch_bounds__(512, 4) void proj_gemm(const bf16* __restrict__ A,
                                                    const bf16* __restrict__ B,
                                                    float* __restrict__ out) {
    __shared__ __align__(16) char smem[49152]; // A 32K + B 16K
    bf16* As = (bf16*)smem;
    bf16* Bs = (bf16*)(smem + 32768);
    const int tid = threadIdx.x, lane = tid & 63, wid = tid >> 6;
    const int wr = wid >> 1, wc = wid & 1;   // 4x2 wave grid over 256x128
    const int lm = lane & 15, hi = lane >> 4;
    const int bid = blockIdx.x;               // 256 blocks: 64 row-panels x 4 col-panels
    const int swz = (bid & 7) * 32 + (bid >> 3); // XCD swizzle
    const int brow = (swz & 63) * 256;
    const int bcol = (swz >> 6) * 128;

    f32x4 acc[4][4] = {};
    for (int k0 = 0; k0 < 512; k0 += 64) {
        __syncthreads();
#pragma unroll
        for (int i = 0; i < 4; ++i) {         // A: 2048 chunks (256x64 bf16)
            int c = i * 512 + tid;
            int f = c >> 6, l = c & 63;
            int row = (f >> 1) * 16 + (l & 15);
            int kc = (f & 1) * 32 + (l >> 4) * 8;
            gload16(A + (size_t)(brow + row) * 512 + k0 + kc, As + c * 8);
        }
#pragma unroll
        for (int i = 0; i < 2; ++i) {         // B: 1024 chunks (128x64 bf16)
            int c = i * 512 + tid;
            int f = c >> 6, l = c & 63;
            int row = (f >> 1) * 16 + (l & 15);
            int kc = (f & 1) * 32 + (l >> 4) * 8;
            gload16(B + (size_t)(bcol + row) * 512 + k0 + kc, Bs + c * 8);
        }
        asm volatile("s_waitcnt vmcnt(0)" ::: "memory");
        __syncthreads();
#pragma unroll
        for (int kk = 0; kk < 2; ++kk) {
            bf16x8 af[4], bfr[4];
#pragma unroll
            for (int m = 0; m < 4; ++m)
                af[m] = *(const bf16x8*)(As + (((wr * 4 + m) * 2 + kk) * 64 + lane) * 8);
#pragma unroll
            for (int n = 0; n < 4; ++n)
                bfr[n] = *(const bf16x8*)(Bs + (((wc * 4 + n) * 2 + kk) * 64 + lane) * 8);
            __builtin_amdgcn_s_setprio(1);
#pragma unroll
            for (int m = 0; m < 4; ++m)
#pragma unroll
                for (int n = 0; n < 4; ++n) mfma16(acc[m][n], af[m], bfr[n]);
            __builtin_amdgcn_s_setprio(0);
        }
    }
#pragma unroll
    for (int m = 0; m < 4; ++m)
#pragma unroll
        for (int n = 0; n < 4; ++n)
#pragma unroll
            for (int r = 0; r < 4; ++r) {
                int i = brow + wr * 64 + m * 16 + hi * 4 + r;
                int j = bcol + wc * 64 + n * 16 + lm;
                out[(size_t)i * DIM_ + j] = acc[m][n][r];
            }
}

extern "C" void kernel_launch(void* const* d_in, const int* in_sizes, int n_in,
                              void* d_out, int out_size, void* d_ws, size_t ws_size,
                              hipStream_t stream) {
    const float* x  = (const float*)d_in[0];
    const float* wq = (const float*)d_in[1];
    const float* wk = (const float*)d_in[2];
    const float* wv = (const float*)d_in[3];
    const float* wp = (const float*)d_in[4];
    if (ws_size < WS_NEEDED) return;

    char* ws = (char*)d_ws;
    bf16* xb    = (bf16*)(ws + OFF_XB);
    bf16* wqkv  = (bf16*)(ws + OFF_WQKV);
    bf16* wpb   = (bf16*)(ws + OFF_WP);
    float* cosT = (float*)(ws + OFF_COS);
    float* sinT = (float*)(ws + OFF_SIN);
    bf16* qt    = (bf16*)(ws + OFF_QT);
    bf16* kt    = (bf16*)(ws + OFF_KT);
    bf16* vt    = (bf16*)(ws + OFF_VT);
    bf16* y     = (bf16*)(ws + OFF_Y);

    prep_kernel<<<2048, 256, 0, stream>>>(x, wq, wk, wv, wp, xb, wqkv, wpb, cosT, sinT);

    qkv_gemm<<<512, 512, 0, stream>>>(xb, wqkv, qt, kt, vt, cosT, sinT);

    attn_kernel<<<1024, 512, 0, stream>>>(qt, kt, vt, y);

    proj_gemm<<<256, 512, 0, stream>>>(y, wpb, (float*)d_out);
}

// Round 23
// 126.983 us; speedup vs baseline: 1.0257x; 1.0257x over previous
//
#include <hip/hip_runtime.h>
#include <hip/hip_bf16.h>
#include <stdint.h>

typedef __bf16 bf16;
typedef __bf16 bf16x8 __attribute__((ext_vector_type(8)));
typedef __bf16 bf16x4 __attribute__((ext_vector_type(4)));
typedef float f32x4 __attribute__((ext_vector_type(4)));

#define T_SEQ 2048
#define DIM_ 512
#define NH_ 8
#define NKV_ 4
#define HD_ 64
#define BT_ (8 * T_SEQ) /* 16384 token rows */
#define NEG_INF (-1e30f)
#define EPS_ 1.1920928955078125e-07f
#define QSCALE 0.18033688011112042f /* 0.125 * log2(e): attn uses exp2 */
#define SMAX 12.0f /* fixed softmax max: |score| <= 64*0.125*log2e = 11.54 < 12 */

// workspace layout (bytes)
#define OFF_XB   (size_t)(0)
#define OFF_WQKV (size_t)(16777216)
#define OFF_WP   (size_t)(17825792)
#define OFF_COS  (size_t)(18350080)
#define OFF_SIN  (size_t)(18612224)
#define OFF_QT   (size_t)(18874368)
#define OFF_KT   (size_t)(35651584)
#define OFF_VT   (size_t)(44040192)
#define OFF_Y    (size_t)(52428800)
#define WS_NEEDED (size_t)(69206016)

__device__ inline void mfma16(f32x4& acc, bf16x8 a, bf16x8 b) {
    acc = __builtin_amdgcn_mfma_f32_16x16x32_bf16(a, b, acc, 0, 0, 0);
}

// async global->LDS, 16B per lane. LDS dest is wave-uniform base + lane*16;
// the per-lane GLOBAL address carries the permutation (m173 pattern).
typedef const __attribute__((address_space(1))) uint8_t* gas_ptr;
typedef __attribute__((address_space(3))) uint8_t* las_ptr;
__device__ inline void gload16(const bf16* g, bf16* l) {
    __builtin_amdgcn_global_load_lds((gas_ptr)(const void*)g, (las_ptr)(void*)l, 16, 0, 0);
}

__device__ inline bf16x4 cvt4(const float4& a) {
    bf16x4 v;
    v[0] = (bf16)a.x; v[1] = (bf16)a.y; v[2] = (bf16)a.z; v[3] = (bf16)a.w;
    return v;
}

// ---------------- prep: VECTORIZED fp32 -> bf16 casts + stacked W + rope tables ----------------
__global__ void prep_kernel(const float* __restrict__ x, const float* __restrict__ wq,
                            const float* __restrict__ wk, const float* __restrict__ wv,
                            const float* __restrict__ wp,
                            bf16* __restrict__ xb, bf16* __restrict__ wqkv,
                            bf16* __restrict__ wpb, float* __restrict__ cosT,
                            float* __restrict__ sinT) {
    int tid = blockIdx.x * blockDim.x + threadIdx.x;
    int stride = gridDim.x * blockDim.x;
    for (int i = tid; i < BT_ * DIM_ / 4; i += stride)
        *(bf16x4*)(xb + (size_t)i * 4) = cvt4(((const float4*)x)[i]);
    for (int i = tid; i < 1024 * 512 / 4; i += stride) {
        int e = i * 4;
        int j = e >> 9, k = e & 511;
        const float* src;
        if (j < 512) src = wq + (size_t)j * 512 + k;
        else if (j < 768) src = wk + (size_t)(j - 512) * 512 + k;
        else src = wv + (size_t)(j - 768) * 512 + k;
        *(bf16x4*)(wqkv + (size_t)e) = cvt4(*(const float4*)src);
    }
    for (int i = tid; i < 512 * 512 / 4; i += stride)
        *(bf16x4*)(wpb + (size_t)i * 4) = cvt4(((const float4*)wp)[i]);
    for (int i = tid; i < T_SEQ * 32; i += stride) {
        int t = i >> 5, d = i & 31;
        float inv = powf(10000.0f, -(float)d * (1.0f / 32.0f));
        float f = (float)t * inv;
        cosT[i] = cosf(f);
        sinT[i] = sinf(f);
    }
}

// ---------------- QKV GEMM: 256x128 tile, 8 waves + fused RMSNorm + RoPE epilogue (R21) ----------------
__global__ __launch_bounds__(512, 4) void qkv_gemm(const bf16* __restrict__ A,
                                                   const bf16* __restrict__ B,
                                                   bf16* __restrict__ qt,
                                                   bf16* __restrict__ kt,
                                                   bf16* __restrict__ vt,
                                                   const float* __restrict__ cosT,
                                                   const float* __restrict__ sinT) {
    __shared__ __align__(16) char smem[49152]; // loop: A(32K)+B(16K); epilogue: 8x 32x66 bf16 (33.8K)
    bf16* As = (bf16*)smem;
    bf16* Bs = (bf16*)(smem + 32768);
    const int tid = threadIdx.x, lane = tid & 63, wid = tid >> 6;
    const int wr = wid >> 1, wc = wid & 1;   // 4x2 wave grid over 256x128
    const int lm = lane & 15, hi = lane >> 4;
    const int bid = blockIdx.x;               // 512 blocks: 64 row-panels x 8 col-panels
    const int swz = (bid & 7) * 64 + (bid >> 3); // XCD owns one col panel
    const int brow = (swz & 63) * 256;
    const int bcol = (swz >> 6) * 128;

    f32x4 acc[4][4] = {};
    for (int k0 = 0; k0 < 512; k0 += 64) {
        __syncthreads();
#pragma unroll
        for (int i = 0; i < 4; ++i) {         // A: 2048 chunks (256x64 bf16)
            int c = i * 512 + tid;
            int f = c >> 6, l = c & 63;
            int row = (f >> 1) * 16 + (l & 15);
            int kc = (f & 1) * 32 + (l >> 4) * 8;
            gload16(A + (size_t)(brow + row) * 512 + k0 + kc, As + c * 8);
        }
#pragma unroll
        for (int i = 0; i < 2; ++i) {         // B: 1024 chunks (128x64 bf16)
            int c = i * 512 + tid;
            int f = c >> 6, l = c & 63;
            int row = (f >> 1) * 16 + (l & 15);
            int kc = (f & 1) * 32 + (l >> 4) * 8;
            gload16(B + (size_t)(bcol + row) * 512 + k0 + kc, Bs + c * 8);
        }
        asm volatile("s_waitcnt vmcnt(0)" ::: "memory");
        __syncthreads();
#pragma unroll
        for (int kk = 0; kk < 2; ++kk) {
            bf16x8 af[4], bfr[4];
#pragma unroll
            for (int m = 0; m < 4; ++m)
                af[m] = *(const bf16x8*)(As + (((wr * 4 + m) * 2 + kk) * 64 + lane) * 8);
#pragma unroll
            for (int n = 0; n < 4; ++n)
                bfr[n] = *(const bf16x8*)(Bs + (((wc * 4 + n) * 2 + kk) * 64 + lane) * 8);
            __builtin_amdgcn_s_setprio(1);
#pragma unroll
            for (int m = 0; m < 4; ++m)
#pragma unroll
                for (int n = 0; n < 4; ++n) mfma16(acc[m][n], af[m], bfr[n]);
            __builtin_amdgcn_s_setprio(0);
        }
    }
    __syncthreads(); // staging reads complete; smem now the per-wave transpose buffers

    bf16* Tb = (bf16*)smem + wid * 2112; // 32 x 66 per wave (wave-private)
    const int wcol = bcol + wc * 64;     // 64-aligned -> whole wave is one head type
    const int ctype = (wcol < 512) ? 0 : (wcol < 768 ? 1 : 2);
    const int i0 = brow + wr * 64;
    const int b = i0 >> 11, tt = i0 & (T_SEQ - 1);

#pragma unroll
    for (int h2 = 0; h2 < 2; ++h2) {
        if (ctype < 2) {
#pragma unroll
            for (int mm = 0; mm < 2; ++mm) {
                const int m = h2 * 2 + mm;
#pragma unroll
                for (int r = 0; r < 4; ++r) {
                    float v0 = acc[m][0][r], v1 = acc[m][1][r];
                    float v2 = acc[m][2][r], v3 = acc[m][3][r];
                    float ss = v0 * v0 + v1 * v1 + v2 * v2 + v3 * v3;
                    ss += __shfl_xor(ss, 1);
                    ss += __shfl_xor(ss, 2);
                    ss += __shfl_xor(ss, 4);
                    ss += __shfl_xor(ss, 8);
                    float rinv = rsqrtf(ss * (1.0f / 64.0f) + EPS_);
                    v0 *= rinv; v1 *= rinv; v2 *= rinv; v3 *= rinv;
                    int rl = m * 16 + hi * 4 + r;
                    int t = (i0 + rl) & (T_SEQ - 1);
                    float c0 = cosT[t * 32 + lm], s0 = sinT[t * 32 + lm];
                    float c1 = cosT[t * 32 + 16 + lm], s1 = sinT[t * 32 + 16 + lm];
                    float o0 = v0 * c0 + v2 * s0;
                    float o2 = v2 * c0 - v0 * s0;
                    float o1 = v1 * c1 + v3 * s1;
                    float o3 = v3 * c1 - v1 * s1;
                    if (ctype == 0) { o0 *= QSCALE; o1 *= QSCALE; o2 *= QSCALE; o3 *= QSCALE; }
                    int rloc = mm * 16 + hi * 4 + r;
                    Tb[rloc * 66 + lm]      = (bf16)o0;
                    Tb[rloc * 66 + 16 + lm] = (bf16)o1;
                    Tb[rloc * 66 + 32 + lm] = (bf16)o2;
                    Tb[rloc * 66 + 48 + lm] = (bf16)o3;
                }
            }
        } else {
#pragma unroll
            for (int m = 0; m < 4; ++m)
#pragma unroll
                for (int nn = 0; nn < 2; ++nn) {
                    const int n = h2 * 2 + nn;
#pragma unroll
                    for (int r = 0; r < 4; ++r)
                        Tb[(nn * 16 + lm) * 66 + m * 16 + hi * 4 + r] = (bf16)acc[m][n][r];
                }
        }
        // wave-private buffer: in-wave lgkmcnt ordering suffices (same pattern as attn epilogue)
#pragma unroll
        for (int pp = 0; pp < 4; ++pp) {
            int row = pp * 8 + (lane >> 3); // 0..31
            int ch = lane & 7;
            bf16x8 val = *(const bf16x8*)(Tb + row * 66 + ch * 8);
            if (ctype == 0) {
                int head = wcol >> 6;
                *(bf16x8*)(qt + ((size_t)((b << 3) + head) * T_SEQ + tt + h2 * 32 + row) * 64 + ch * 8) = val;
            } else if (ctype == 1) {
                int head = (wcol - 512) >> 6;
                *(bf16x8*)(kt + ((size_t)((b << 2) + head) * T_SEQ + tt + h2 * 32 + row) * 64 + ch * 8) = val;
            } else {
                int head = (wcol - 768) >> 6;
                *(bf16x8*)(vt + ((size_t)((b << 2) + head) * 64 + h2 * 32 + row) * T_SEQ + tt + ch * 8) = val;
            }
        }
    }
}

// ---------------- causal GQA flash attention: 8-wave blocks, 128-row panels (R17/R20) ----------------
__global__ __launch_bounds__(512, 4) void attn_kernel(const bf16* __restrict__ qt,
                                                      const bf16* __restrict__ kt,
                                                      const bf16* __restrict__ vt,
                                                      bf16* __restrict__ y) {
    __shared__ bf16 Klds[4096];       // 8 frag-slots x 64 lanes x 8 elem
    __shared__ bf16 Vlds[4096];
    __shared__ bf16 Plds[8][1152];    // per-wave P (stride 40) / epilogue transpose (stride 72)
    const int tid = threadIdx.x;
    const int lane = tid & 63, wid = tid >> 6;
    const int lm = lane & 15, hi = lane >> 4;
    const int bid = blockIdx.x;
    const int s4 = bid >> 8;               // 0..3 (dispatch round; 0 = heaviest)
    const int g4 = (bid >> 6) & 3;         // 0..3 (CU slot)
    const int bh = bid & 63;
    const int p = 4 * (3 - s4) + ((g4 + s4) & 3); // Latin square over 16 panels
    const int b = bh >> 3, h = bh & 7, hv = h >> 1;
    const bf16* Q = qt + (size_t)bh * T_SEQ * HD_;
    const bf16* K = kt + (size_t)(b * NKV_ + hv) * T_SEQ * HD_;
    const bf16* V = vt + (size_t)(b * NKV_ + hv) * HD_ * T_SEQ;
    const int qB = p * 128;
    const int qw = qB + wid * 16;
    bf16* Pl = &Plds[wid][0];

    // staging geometry: 512 threads x 1 chunk = full 64x64 K tile (and V tile)
    const int sl0 = tid >> 6, l0 = tid & 63;
    const int gr0 = (sl0 >> 1) * 16 + (l0 & 15);
    const int gc0 = (sl0 & 1) * 32 + (l0 >> 4) * 8;
    const bf16* kg0 = K + (size_t)gr0 * HD_ + gc0;
    const bf16* vg0 = V + (size_t)gr0 * T_SEQ + gc0;
    bf16* kd0 = Klds + (size_t)tid * 8;
    bf16* vd0 = Vlds + (size_t)tid * 8;

    // Q fragments (B-side): lane holds Q[q=qw+lm][d = 32*kk + 8*hi + j]
    bf16x8 qf[2];
#pragma unroll
    for (int kk = 0; kk < 2; ++kk)
        qf[kk] = *(const bf16x8*)(Q + (size_t)(qw + lm) * HD_ + 32 * kk + 8 * hi);

    bf16x8 vones;
#pragma unroll
    for (int j = 0; j < 8; ++j) vones[j] = (bf16)1.0f;

    f32x4 o[4] = {};
    f32x4 lacc = {};

    const int nt = (qB >> 6) + 2;
    for (int t = 0; t < nt; ++t) {
        const int kv0 = t << 6;
        __syncthreads(); // previous tile's compute done before overwrite
        {
            size_t ko = (size_t)kv0 * HD_, vo = (size_t)kv0;
            gload16(kg0 + ko, kd0);
            gload16(vg0 + vo, vd0);
        }
        asm volatile("s_waitcnt vmcnt(0)" ::: "memory");
        __syncthreads();

        if (kv0 <= qw + 15) { // wave-uniform: skip fully-masked tiles
            // ---- QK^T (swapped): s[n] rows = kv (16n+4hi+r), col = q (lm)
            f32x4 s[4] = {};
#pragma unroll
            for (int kk = 0; kk < 2; ++kk) {
                bf16x8 kf[4];
#pragma unroll
                for (int n = 0; n < 4; ++n)
                    kf[n] = *(const bf16x8*)(Klds + ((n * 2 + kk) * 64 + lane) * 8);
                __builtin_amdgcn_s_setprio(1);
#pragma unroll
                for (int n = 0; n < 4; ++n) mfma16(s[n], kf[n], qf[kk]);
                __builtin_amdgcn_s_setprio(0);
            }
            const bool partial = (kv0 + 63 > qw);
            const int qg = qw + lm;
            bf16x4 pw[4];
#pragma unroll
            for (int n = 0; n < 4; ++n)
#pragma unroll
                for (int r = 0; r < 4; ++r) {
                    float xv = s[n][r];
                    if (partial)
                        xv = ((kv0 + 16 * n + 4 * hi + r) <= qg) ? xv : NEG_INF;
                    pw[n][r] = (bf16)__builtin_amdgcn_exp2f(xv - SMAX); // fixed max
                }
            // ---- PV (swapped) in 2 kk-phases; denominator via ones-row MFMA
#pragma unroll
            for (int kk = 0; kk < 2; ++kk) {
                *(bf16x4*)(Pl + lm * 40 + 4 * hi)      = pw[2 * kk];
                *(bf16x4*)(Pl + lm * 40 + 16 + 4 * hi) = pw[2 * kk + 1];
                bf16x8 vf[4], pf;
                pf = *(const bf16x8*)(Pl + lm * 40 + 8 * hi);
#pragma unroll
                for (int nd = 0; nd < 4; ++nd)
                    vf[nd] = *(const bf16x8*)(Vlds + ((nd * 2 + kk) * 64 + lane) * 8);
                __builtin_amdgcn_s_setprio(1);
#pragma unroll
                for (int nd = 0; nd < 4; ++nd) mfma16(o[nd], vf[nd], pf);
                mfma16(lacc, vones, pf); // row of ones: lacc[*] = sum_k P[k][q=lm]
                __builtin_amdgcn_s_setprio(0);
            }
        }
    }

    // epilogue: normalize by lacc[0] (every lane holds its q-column's sum), transpose via LDS
    float rcl = 1.0f / lacc[0];
#pragma unroll
    for (int nd = 0; nd < 4; ++nd) {
        bf16x4 ov;
#pragma unroll
        for (int r = 0; r < 4; ++r) ov[r] = (bf16)(o[nd][r] * rcl);
        *(bf16x4*)(Pl + lm * 72 + nd * 16 + 4 * hi) = ov;
    }
#pragma unroll
    for (int it = 0; it < 2; ++it) {
        int chunk = it * 64 + lane;
        int row = chunk >> 3, dc = (chunk & 7) * 8;
        bf16x8 val = *(const bf16x8*)(Pl + row * 72 + dc);
        *(bf16x8*)(y + (size_t)(b * T_SEQ + qw + row) * DIM_ + h * HD_ + dc) = val;
    }
}

// ---------------- output projection: out[i][j] = sum_k Y[i][k]*Wp[j][k] (R12/R21) ----------------
__global__ __launch_bounds__(256) void proj_gemm(const bf16* __restrict__ A,
                                                 const bf16* __restrict__ B,
                                                 float* __restrict__ out) {
    __shared__ __align__(16) char smem[32768];
    bf16* As = (bf16*)smem;
    bf16* Bs = (bf16*)(smem + 16384);
    const int tid = threadIdx.x, lane = tid & 63, wid = tid >> 6;
    const int wr = wid >> 1, wc = wid & 1;
    const int lm = lane & 15, hi = lane >> 4;
    const int bid = blockIdx.x;
    const int swz = (bid & 7) * 64 + (bid >> 3);
    const int brow = (swz & 127) * 128;
    const int bcol = (swz >> 7) * 128;

    f32x4 acc[4][4] = {};
    for (int k0 = 0; k0 < 512; k0 += 64) {
        __syncthreads();
#pragma unroll
        for (int i = 0; i < 4; ++i) {
            int c = i * 256 + tid;
            int slot = c >> 6, l = c & 63;
            int row = (slot >> 1) * 16 + (l & 15);
            int kc = (slot & 1) * 32 + (l >> 4) * 8;
            gload16(A + (size_t)(brow + row) * 512 + k0 + kc, As + c * 8);
            gload16(B + (size_t)(bcol + row) * 512 + k0 + kc, Bs + c * 8);
        }
        asm volatile("s_waitcnt vmcnt(0)" ::: "memory");
        __syncthreads();
#pragma unroll
        for (int kk = 0; kk < 2; ++kk) {
            bf16x8 af[4], bfr[4];
#pragma unroll
            for (int m = 0; m < 4; ++m)
                af[m] = *(const bf16x8*)(As + (((wr * 4 + m) * 2 + kk) * 64 + lane) * 8);
#pragma unroll
            for (int n = 0; n < 4; ++n)
                bfr[n] = *(const bf16x8*)(Bs + (((wc * 4 + n) * 2 + kk) * 64 + lane) * 8);
            __builtin_amdgcn_s_setprio(1);
#pragma unroll
            for (int m = 0; m < 4; ++m)
#pragma unroll
                for (int n = 0; n < 4; ++n) mfma16(acc[m][n], af[m], bfr[n]);
            __builtin_amdgcn_s_setprio(0);
        }
    }
#pragma unroll
    for (int m = 0; m < 4; ++m)
#pragma unroll
        for (int n = 0; n < 4; ++n)
#pragma unroll
            for (int r = 0; r < 4; ++r) {
                int i = brow + wr * 64 + m * 16 + hi * 4 + r;
                int j = bcol + wc * 64 + n * 16 + lm;
                out[(size_t)i * DIM_ + j] = acc[m][n][r];
            }
}

extern "C" void kernel_launch(void* const* d_in, const int* in_sizes, int n_in,
                              void* d_out, int out_size, void* d_ws, size_t ws_size,
                              hipStream_t stream) {
    const float* x  = (const float*)d_in[0];
    const float* wq = (const float*)d_in[1];
    const float* wk = (const float*)d_in[2];
    const float* wv = (const float*)d_in[3];
    const float* wp = (const float*)d_in[4];
    if (ws_size < WS_NEEDED) return;

    char* ws = (char*)d_ws;
    bf16* xb    = (bf16*)(ws + OFF_XB);
    bf16* wqkv  = (bf16*)(ws + OFF_WQKV);
    bf16* wpb   = (bf16*)(ws + OFF_WP);
    float* cosT = (float*)(ws + OFF_COS);
    float* sinT = (float*)(ws + OFF_SIN);
    bf16* qt    = (bf16*)(ws + OFF_QT);
    bf16* kt    = (bf16*)(ws + OFF_KT);
    bf16* vt    = (bf16*)(ws + OFF_VT);
    bf16* y     = (bf16*)(ws + OFF_Y);

    prep_kernel<<<2048, 256, 0, stream>>>(x, wq, wk, wv, wp, xb, wqkv, wpb, cosT, sinT);

    qkv_gemm<<<512, 512, 0, stream>>>(xb, wqkv, qt, kt, vt, cosT, sinT);

    attn_kernel<<<1024, 512, 0, stream>>>(qt, kt, vt, y);

    proj_gemm<<<512, 256, 0, stream>>>(y, wpb, (float*)d_out);
}